// Round 1
// baseline (490.515 us; speedup 1.0000x reference)
//
#include <hip/hip_runtime.h>
#include <math.h>

constexpr int CB = 4, CN = 512, CD = 256, CH = 8, CHD = 32, CP = 3;
constexpr float CEPS = 1e-5f;
constexpr int M_ROWS = CB * CN; // 2048

// workspace layout (offsets in floats)
constexpr size_t OFF_QKV  = 0;                                  // [B,N,3D]
constexpr size_t OFF_LOG  = OFF_QKV + (size_t)CB*CN*3*CD;       // [B,H,N,N]
constexpr size_t OFF_AOUT = OFF_LOG + (size_t)CB*CH*CN*CN;      // [B,N,D]
constexpr size_t OFF_PRE1 = OFF_AOUT + (size_t)CB*CN*CD;        // [B,N,D]
constexpr size_t OFF_X1   = OFF_PRE1 + (size_t)CB*CN*CD;        // [B,N,D]
constexpr size_t OFF_H1   = OFF_X1 + (size_t)CB*CN*CD;          // [B,N,4D]
constexpr size_t OFF_PRE2 = OFF_H1 + (size_t)CB*CN*4*CD;        // [B,N,D]
constexpr size_t OFF_PACK = OFF_PRE2 + (size_t)CB*CN*CD;        // 256*12
constexpr size_t OFF_MASK = OFF_PACK + 256*12;                  // B*N ints

// ---------------- mask decode (robust to bool / int32 / float32) -----------
__global__ void decode_mask_kernel(const unsigned char* __restrict__ raw,
                                   int* __restrict__ mout) {
  __shared__ int mode_max;
  if (threadIdx.x == 0) mode_max = 0;
  __syncthreads();
  int lm = 0;
  for (int i = threadIdx.x; i < CB*CN; i += 256)
    if ((i & 3) != 0) lm = max(lm, (int)raw[i]);
  atomicMax(&mode_max, lm);
  __syncthreads();
  int mv = mode_max;
  for (int i = threadIdx.x; i < CB*CN; i += 256) {
    int val;
    if (mv == 0)      val = (((const int*)raw)[i] != 0);          // int32 0/1
    else if (mv == 1) val = (raw[i] != 0);                        // bool bytes
    else              val = (((const unsigned int*)raw)[i] != 0); // f32 bits
    mout[i] = val;
  }
}

// ---------------- pack pair-MLP params: 12 floats per channel --------------
__global__ void pack_kernel(const float* __restrict__ Wp1,
                            const float* __restrict__ bp1,
                            const float* __restrict__ Wp2,
                            float* __restrict__ packed) {
  int c = threadIdx.x; // 256
  packed[c*12+0] = Wp1[0*CD + c];
  packed[c*12+1] = Wp1[1*CD + c];
  packed[c*12+2] = Wp1[2*CD + c];
  packed[c*12+3] = bp1[c];
#pragma unroll
  for (int h = 0; h < 8; h++) packed[c*12+4+h] = Wp2[c*8+h];
}

// ---------------- generic tiled GEMM: C = act(A@W + bias + R) --------------
// ACT: 0 none, 1 exact GELU
template<int ACT, bool HASB, bool HASR>
__global__ __launch_bounds__(256) void gemm_kernel(
    const float* __restrict__ A, const float* __restrict__ W,
    const float* __restrict__ bias, const float* __restrict__ R,
    float* __restrict__ C, int M, int Nc, int K) {
  __shared__ float As[32][68];
  __shared__ float Ws[32][68];
  const int tid = threadIdx.x;
  const int tx = tid & 15, ty = tid >> 4;
  const int bm = blockIdx.y * 64, bn = blockIdx.x * 64;
  float acc[4][4] = {};
  for (int k0 = 0; k0 < K; k0 += 32) {
#pragma unroll
    for (int t = tid; t < 2048; t += 256) {
      int m = t >> 5, kk = t & 31;
      As[kk][m] = A[(size_t)(bm + m) * K + (k0 + kk)];
    }
#pragma unroll
    for (int t = tid; t < 2048; t += 256) {
      int r = t >> 6, c = t & 63;
      Ws[r][c] = W[(size_t)(k0 + r) * Nc + (bn + c)];
    }
    __syncthreads();
#pragma unroll 8
    for (int kk = 0; kk < 32; kk++) {
      float4 a = *(const float4*)&As[kk][ty * 4];
      float4 w = *(const float4*)&Ws[kk][tx * 4];
      float av[4] = {a.x, a.y, a.z, a.w};
      float wv[4] = {w.x, w.y, w.z, w.w};
#pragma unroll
      for (int i = 0; i < 4; i++)
#pragma unroll
        for (int j = 0; j < 4; j++)
          acc[i][j] = fmaf(av[i], wv[j], acc[i][j]);
    }
    __syncthreads();
  }
#pragma unroll
  for (int i = 0; i < 4; i++) {
    int m = bm + ty * 4 + i;
#pragma unroll
    for (int j = 0; j < 4; j++) {
      int n = bn + tx * 4 + j;
      float v = acc[i][j];
      if (HASB) v += bias[n];
      if (HASR) v += R[(size_t)m * Nc + n];
      if (ACT == 1) v = 0.5f * v * (1.0f + erff(v * 0.70710678118654752f));
      C[(size_t)m * Nc + n] = v;
    }
  }
}

// ---------------- pairwise bias MLP -> logits[b,h,i,j] ---------------------
__global__ __launch_bounds__(256) void pair_bias_kernel(
    const float* __restrict__ pf, const float* __restrict__ packed,
    const float* __restrict__ bp2, float* __restrict__ logits) {
  const int blk = blockIdx.x;       // b*CN + i
  const int b = blk / CN, i = blk % CN;
  const int tx = threadIdx.x;
  const float* pfrow = pf + (size_t)(b * CN + i) * CN * CP;
  const int ja = tx, jb = tx + 256;
  float f0a = pfrow[ja*3+0], f1a = pfrow[ja*3+1], f2a = pfrow[ja*3+2];
  float f0b = pfrow[jb*3+0], f1b = pfrow[jb*3+1], f2b = pfrow[jb*3+2];
  float acca[8] = {0,0,0,0,0,0,0,0};
  float accb[8] = {0,0,0,0,0,0,0,0};
  for (int c = 0; c < 256; c++) {
    const float4* pk = (const float4*)(packed + c * 12);
    float4 p0 = pk[0];
    float4 p1 = pk[1];
    float4 p2 = pk[2];
    float ha = fmaf(f0a, p0.x, fmaf(f1a, p0.y, fmaf(f2a, p0.z, p0.w)));
    float hb = fmaf(f0b, p0.x, fmaf(f1b, p0.y, fmaf(f2b, p0.z, p0.w)));
    ha = fmaxf(ha, 0.f); hb = fmaxf(hb, 0.f);
    acca[0] = fmaf(ha, p1.x, acca[0]); acca[1] = fmaf(ha, p1.y, acca[1]);
    acca[2] = fmaf(ha, p1.z, acca[2]); acca[3] = fmaf(ha, p1.w, acca[3]);
    acca[4] = fmaf(ha, p2.x, acca[4]); acca[5] = fmaf(ha, p2.y, acca[5]);
    acca[6] = fmaf(ha, p2.z, acca[6]); acca[7] = fmaf(ha, p2.w, acca[7]);
    accb[0] = fmaf(hb, p1.x, accb[0]); accb[1] = fmaf(hb, p1.y, accb[1]);
    accb[2] = fmaf(hb, p1.z, accb[2]); accb[3] = fmaf(hb, p1.w, accb[3]);
    accb[4] = fmaf(hb, p2.x, accb[4]); accb[5] = fmaf(hb, p2.y, accb[5]);
    accb[6] = fmaf(hb, p2.z, accb[6]); accb[7] = fmaf(hb, p2.w, accb[7]);
  }
#pragma unroll
  for (int h = 0; h < 8; h++) {
    float bb = bp2[h];
    size_t idx = ((size_t)(b * CH + h) * CN + i) * CN;
    logits[idx + ja] = acca[h] + bb;
    logits[idx + jb] = accb[h] + bb;
  }
}

// ---------------- logits += scale * Q K^T ----------------------------------
__global__ __launch_bounds__(256) void qk_kernel(
    const float* __restrict__ qkv, float* __restrict__ logits) {
  int bh = blockIdx.y; int b = bh >> 3, h = bh & 7;
  int ti = blockIdx.x >> 4, tj = blockIdx.x & 15; // CN/32 = 16
  int i0 = ti * 32, j0 = tj * 32;
  __shared__ float Qs[32][33], Ks[32][33];
  int d = threadIdx.x & 31, r8 = threadIdx.x >> 5;
#pragma unroll
  for (int rr = r8; rr < 32; rr += 8) {
    Qs[rr][d] = qkv[(size_t)(b*CN + i0 + rr)*(3*CD) + h*CHD + d];
    Ks[rr][d] = qkv[(size_t)(b*CN + j0 + rr)*(3*CD) + CD + h*CHD + d];
  }
  __syncthreads();
  int jl = d, ig = r8;
  float acc0 = 0, acc1 = 0, acc2 = 0, acc3 = 0;
#pragma unroll 8
  for (int dd = 0; dd < 32; dd++) {
    float kv = Ks[jl][dd];
    acc0 = fmaf(Qs[ig*4+0][dd], kv, acc0);
    acc1 = fmaf(Qs[ig*4+1][dd], kv, acc1);
    acc2 = fmaf(Qs[ig*4+2][dd], kv, acc2);
    acc3 = fmaf(Qs[ig*4+3][dd], kv, acc3);
  }
  const float scale = 0.17677669529663687f; // 32^-0.5
  size_t base = (size_t)(b * CH + h) * CN;
  logits[(base + i0 + ig*4+0)*CN + j0 + jl] += acc0 * scale;
  logits[(base + i0 + ig*4+1)*CN + j0 + jl] += acc1 * scale;
  logits[(base + i0 + ig*4+2)*CN + j0 + jl] += acc2 * scale;
  logits[(base + i0 + ig*4+3)*CN + j0 + jl] += acc3 * scale;
}

// ---------------- masked softmax over j ------------------------------------
__global__ __launch_bounds__(256) void softmax_kernel(
    float* __restrict__ logits, const int* __restrict__ mask) {
  int row = blockIdx.x * 4 + (threadIdx.x >> 6); // [0, B*H*N)
  int lane = threadIdx.x & 63;
  int b = row >> 12; // row / (CH*CN)
  float* L = logits + (size_t)row * CN;
  const int* mrow = mask + b * CN;
  float v[8]; float mx = -3.0e38f;
#pragma unroll
  for (int t = 0; t < 8; t++) {
    int j = lane + t * 64;
    float x = L[j];
    x = mrow[j] ? x : -1e9f;
    v[t] = x;
    mx = fmaxf(mx, x);
  }
#pragma unroll
  for (int off = 32; off > 0; off >>= 1) mx = fmaxf(mx, __shfl_xor(mx, off));
  float s = 0.f;
#pragma unroll
  for (int t = 0; t < 8; t++) { v[t] = __expf(v[t] - mx); s += v[t]; }
#pragma unroll
  for (int off = 32; off > 0; off >>= 1) s += __shfl_xor(s, off);
  float inv = 1.0f / s;
#pragma unroll
  for (int t = 0; t < 8; t++) L[lane + t * 64] = v[t] * inv;
}

// ---------------- out = attn @ V -------------------------------------------
__global__ __launch_bounds__(256) void av_kernel(
    const float* __restrict__ logits, const float* __restrict__ qkv,
    float* __restrict__ outp) {
  int bid = blockIdx.x;
  int it = bid & 63;            // CN/8 = 64 tiles
  int bh = bid >> 6; int b = bh >> 3, h = bh & 7;
  int i0 = it * 8;
  __shared__ float Vs[32][33];
  __shared__ float Ps[8][33];
  int d = threadIdx.x & 31, ir = threadIdx.x >> 5;
  float acc = 0.f;
  const float* Lb = logits + ((size_t)(b * CH + h) * CN + i0) * CN;
  for (int j0 = 0; j0 < CN; j0 += 32) {
#pragma unroll
    for (int rr = ir; rr < 32; rr += 8)
      Vs[rr][d] = qkv[(size_t)(b*CN + j0 + rr)*(3*CD) + 2*CD + h*CHD + d];
    Ps[ir][d] = Lb[(size_t)ir * CN + j0 + d];
    __syncthreads();
#pragma unroll 8
    for (int jj = 0; jj < 32; jj++)
      acc = fmaf(Ps[ir][jj], Vs[jj][d], acc);
    __syncthreads();
  }
  outp[(size_t)(b*CN + i0 + ir)*CD + h*CHD + d] = acc;
}

// ---------------- LayerNorm over D=256 (wave per row) ----------------------
__global__ __launch_bounds__(256) void ln_kernel(
    const float* __restrict__ in, const float* __restrict__ g,
    const float* __restrict__ be, float* __restrict__ op) {
  int row = blockIdx.x * 4 + (threadIdx.x >> 6);
  int lane = threadIdx.x & 63;
  const float* x = in + (size_t)row * CD;
  float4 v = *(const float4*)&x[lane * 4];
  float s  = v.x + v.y + v.z + v.w;
  float ss = v.x*v.x + v.y*v.y + v.z*v.z + v.w*v.w;
#pragma unroll
  for (int off = 32; off > 0; off >>= 1) {
    s  += __shfl_xor(s, off);
    ss += __shfl_xor(ss, off);
  }
  float mean = s * (1.0f / CD);
  float var  = ss * (1.0f / CD) - mean * mean;
  float inv  = rsqrtf(var + CEPS);
  float4 gg = *(const float4*)&g[lane * 4];
  float4 bb = *(const float4*)&be[lane * 4];
  float4 o;
  o.x = (v.x - mean) * inv * gg.x + bb.x;
  o.y = (v.y - mean) * inv * gg.y + bb.y;
  o.z = (v.z - mean) * inv * gg.z + bb.z;
  o.w = (v.w - mean) * inv * gg.w + bb.w;
  *(float4*)&op[(size_t)row * CD + lane * 4] = o;
}

extern "C" void kernel_launch(void* const* d_in, const int* in_sizes, int n_in,
                              void* d_out, int out_size, void* d_ws, size_t ws_size,
                              hipStream_t stream) {
  (void)in_sizes; (void)n_in; (void)out_size; (void)ws_size;
  const float* x    = (const float*)d_in[0];
  const void*  mask = d_in[1];
  const float* pf   = (const float*)d_in[2];
  const float* Wqkv = (const float*)d_in[3];
  const float* Wout = (const float*)d_in[4];
  const float* bout = (const float*)d_in[5];
  const float* Wp1  = (const float*)d_in[6];
  const float* bp1  = (const float*)d_in[7];
  const float* Wp2  = (const float*)d_in[8];
  const float* bp2  = (const float*)d_in[9];
  const float* Wf1  = (const float*)d_in[10];
  const float* bf1  = (const float*)d_in[11];
  const float* Wf2  = (const float*)d_in[12];
  const float* bf2  = (const float*)d_in[13];
  const float* g1   = (const float*)d_in[14];
  const float* b1   = (const float*)d_in[15];
  const float* g2   = (const float*)d_in[16];
  const float* b2   = (const float*)d_in[17];

  float* ws     = (float*)d_ws;
  float* qkv    = ws + OFF_QKV;
  float* logits = ws + OFF_LOG;
  float* aout   = ws + OFF_AOUT;
  float* pre1   = ws + OFF_PRE1;
  float* x1     = ws + OFF_X1;
  float* h1     = ws + OFF_H1;
  float* pre2   = ws + OFF_PRE2;
  float* packed = ws + OFF_PACK;
  int*   maskd  = (int*)(ws + OFF_MASK);
  float* out    = (float*)d_out;

  hipLaunchKernelGGL(decode_mask_kernel, dim3(1), dim3(256), 0, stream,
                     (const unsigned char*)mask, maskd);
  hipLaunchKernelGGL(pack_kernel, dim3(1), dim3(256), 0, stream,
                     Wp1, bp1, Wp2, packed);
  // qkv = x @ Wqkv
  hipLaunchKernelGGL((gemm_kernel<0,false,false>), dim3(12, 32), dim3(256), 0, stream,
                     x, Wqkv, nullptr, nullptr, qkv, M_ROWS, 3*CD, CD);
  // logits = pair-bias MLP
  hipLaunchKernelGGL(pair_bias_kernel, dim3(CB*CN), dim3(256), 0, stream,
                     pf, packed, bp2, logits);
  // logits += scale * Q K^T
  hipLaunchKernelGGL(qk_kernel, dim3(256, CB*CH), dim3(256), 0, stream,
                     qkv, logits);
  // masked softmax
  hipLaunchKernelGGL(softmax_kernel, dim3(CB*CH*CN/4), dim3(256), 0, stream,
                     logits, maskd);
  // attn @ V
  hipLaunchKernelGGL(av_kernel, dim3(CB*CH*CN/8), dim3(256), 0, stream,
                     logits, qkv, aout);
  // out proj + residual
  hipLaunchKernelGGL((gemm_kernel<0,true,true>), dim3(4, 32), dim3(256), 0, stream,
                     aout, Wout, bout, x, pre1, M_ROWS, CD, CD);
  hipLaunchKernelGGL(ln_kernel, dim3(M_ROWS/4), dim3(256), 0, stream,
                     pre1, g1, b1, x1);
  // FFN
  hipLaunchKernelGGL((gemm_kernel<1,true,false>), dim3(16, 32), dim3(256), 0, stream,
                     x1, Wf1, bf1, nullptr, h1, M_ROWS, 4*CD, CD);
  hipLaunchKernelGGL((gemm_kernel<0,true,true>), dim3(4, 32), dim3(256), 0, stream,
                     h1, Wf2, bf2, x1, pre2, M_ROWS, CD, 4*CD);
  hipLaunchKernelGGL(ln_kernel, dim3(M_ROWS/4), dim3(256), 0, stream,
                     pre2, g2, b2, out);
}

// Round 4
// 367.193 us; speedup vs baseline: 1.3359x; 1.3359x over previous
//
#include <hip/hip_runtime.h>
#include <math.h>

typedef unsigned short u16;
typedef short s16x8 __attribute__((ext_vector_type(8)));
typedef float f32x4 __attribute__((ext_vector_type(4)));
typedef unsigned int u32x2 __attribute__((ext_vector_type(2)));

constexpr int CB = 4, CN = 512, CD = 256, CH = 8, CHD = 32;
constexpr float CEPS = 1e-5f;
constexpr int M_ROWS = CB * CN; // 2048
constexpr float QSCALE = 0.17677669529663687f; // 32^-0.5

// ---- workspace layout (byte offsets) ----
constexpr size_t O_XB    = 0;                      // u16 [2048][256]
constexpr size_t O_QB    = 1048576;                // u16 [2048][256] (pre-scaled)
constexpr size_t O_KB    = 2097152;                // u16 [2048][256]
constexpr size_t O_VT    = 3145728;                // u16 [4][8][32][512]
constexpr size_t O_WQKVT = 4194304;                // u16 [768][256]
constexpr size_t O_WOUTT = O_WQKVT + 393216;       // u16 [256][256]
constexpr size_t O_WF1T  = O_WOUTT + 131072;       // u16 [1024][256]
constexpr size_t O_WF2T  = O_WF1T + 524288;        // u16 [256][1024]
constexpr size_t O_WP2T  = O_WF2T + 524288;        // u16 [16][256] (pad h>=8 = 0)
constexpr size_t O_PACKED= O_WP2T + 8192;          // f32 [256][4] (w0,w1,w2,b)
constexpr size_t O_MASKD = O_PACKED + 4096;        // int [2048]
constexpr size_t O_BIAS  = O_MASKD + 8192;         // u16 [4][8][512][512]
constexpr size_t O_AOUT  = O_BIAS + 16777216;      // u16 [2048][256]
constexpr size_t O_PRE1  = O_AOUT + 1048576;       // f32 [2048][256]
constexpr size_t O_X1F   = O_PRE1 + 2097152;       // f32 [2048][256]
constexpr size_t O_X1B   = O_X1F + 2097152;        // u16 [2048][256]
constexpr size_t O_H1B   = O_X1B + 1048576;        // u16 [2048][1024]
constexpr size_t O_PRE2  = O_H1B + 4194304;        // f32 [2048][256]

__device__ inline u16 f2b(float f) {
  union { float f; unsigned u; } v{f};
  return (u16)((v.u + 0x7FFFu + ((v.u >> 16) & 1u)) >> 16);
}
__device__ inline float b2f(u16 b) {
  union { unsigned u; float f; } v{(unsigned)b << 16};
  return v.f;
}
__device__ inline f32x4 MFMA(s16x8 a, s16x8 b, f32x4 c) {
  return __builtin_amdgcn_mfma_f32_16x16x32_bf16(a, b, c, 0, 0, 0);
}

// ---------------- mask decode (robust to bool / int32 / float32) -----------
__global__ void decode_mask_kernel(const unsigned char* __restrict__ raw,
                                   int* __restrict__ mout) {
  __shared__ int mode_max;
  if (threadIdx.x == 0) mode_max = 0;
  __syncthreads();
  int lm = 0;
  for (int i = threadIdx.x; i < CB*CN; i += 256)
    if ((i & 3) != 0) lm = max(lm, (int)raw[i]);
  atomicMax(&mode_max, lm);
  __syncthreads();
  int mv = mode_max;
  for (int i = threadIdx.x; i < CB*CN; i += 256) {
    int val;
    if (mv == 0)      val = (((const int*)raw)[i] != 0);
    else if (mv == 1) val = (raw[i] != 0);
    else              val = (((const unsigned int*)raw)[i] != 0);
    mout[i] = val;
  }
}

// ---------------- prep: bf16 convert + weight transposes -------------------
__global__ __launch_bounds__(256) void prep_kernel(
    const float* __restrict__ x, const float* __restrict__ Wqkv,
    const float* __restrict__ Wout, const float* __restrict__ Wf1,
    const float* __restrict__ Wf2, const float* __restrict__ Wp2,
    const float* __restrict__ Wp1, const float* __restrict__ bp1,
    u16* __restrict__ xb, u16* __restrict__ wqkvt, u16* __restrict__ woutt,
    u16* __restrict__ wf1t, u16* __restrict__ wf2t, u16* __restrict__ wp2t,
    float* __restrict__ packed) {
  int blk = blockIdx.x, tid = threadIdx.x;
  if (blk < 256) {            // x -> xb
    for (int t = tid; t < 512; t += 256) {
      float4 v = ((const float4*)x)[blk * 512 + t];
      u16 o0 = f2b(v.x), o1 = f2b(v.y), o2 = f2b(v.z), o3 = f2b(v.w);
      u32x2 w; w.x = (unsigned)o0 | ((unsigned)o1 << 16);
      w.y = (unsigned)o2 | ((unsigned)o3 << 16);
      *(u32x2*)(xb + (size_t)(blk * 512 + t) * 4) = w;
    }
  } else if (blk < 352) {     // Wqkv^T
    int o0 = (blk - 256) * 2048;
    for (int t = tid; t < 2048; t += 256) {
      int o = o0 + t, n = o >> 8, k = o & 255;
      wqkvt[o] = f2b(Wqkv[k * 768 + n]);
    }
  } else if (blk < 384) {     // Wout^T
    int o0 = (blk - 352) * 2048;
    for (int t = tid; t < 2048; t += 256) {
      int o = o0 + t, n = o >> 8, k = o & 255;
      woutt[o] = f2b(Wout[k * 256 + n]);
    }
  } else if (blk < 512) {     // Wf1^T
    int o0 = (blk - 384) * 2048;
    for (int t = tid; t < 2048; t += 256) {
      int o = o0 + t, n = o >> 8, k = o & 255;
      wf1t[o] = f2b(Wf1[k * 1024 + n]);
    }
  } else if (blk < 640) {     // Wf2^T
    int o0 = (blk - 512) * 2048;
    for (int t = tid; t < 2048; t += 256) {
      int o = o0 + t, n = o >> 10, k = o & 1023;
      wf2t[o] = f2b(Wf2[k * 256 + n]);
    }
  } else {                    // Wp2^T (padded) + packed Wp1/bp1
    for (int t = tid; t < 4096; t += 256) {
      int h = t >> 8, c = t & 255;
      wp2t[t] = (h < 8) ? f2b(Wp2[c * 8 + h]) : (u16)0;
    }
    if (tid < 256) {
      float4 p; p.x = Wp1[tid]; p.y = Wp1[256 + tid]; p.z = Wp1[512 + tid];
      p.w = bp1[tid];
      ((float4*)packed)[tid] = p;
    }
  }
}

// ---------------- bf16 MFMA GEMM, 64x64 tile, BK=64 ------------------------
// EPI 0: qkv split (q scaled, k, v transposed)  1: +bias+R -> f32   2: +bias,GELU -> bf16
template<int EPI>
__global__ __launch_bounds__(256) void mgemm(
    const u16* __restrict__ A, const u16* __restrict__ Wt,
    const float* __restrict__ bias, const float* __restrict__ R,
    float* __restrict__ outf, u16* __restrict__ outb,
    u16* __restrict__ qb, u16* __restrict__ kb, u16* __restrict__ vt,
    int M, int N, int K) {
  __shared__ u16 As[64 * 64];
  __shared__ u16 Bs[64 * 64];
  const int tid = threadIdx.x;
  const int lane = tid & 63, w = tid >> 6;
  const int wm = w >> 1, wn = w & 1;
  const int bm = blockIdx.y * 64, bn = blockIdx.x * 64;
  f32x4 fz = {0.f, 0.f, 0.f, 0.f};
  f32x4 acc[2][2] = {{fz, fz}, {fz, fz}};
  for (int k0 = 0; k0 < K; k0 += 64) {
#pragma unroll
    for (int t = tid; t < 512; t += 256) {
      int r = t >> 3, s = t & 7;
      s16x8 v = *(const s16x8*)(A + (size_t)(bm + r) * K + k0 + s * 8);
      *(s16x8*)(As + r * 64 + ((s ^ (r & 7)) << 3)) = v;
    }
#pragma unroll
    for (int t = tid; t < 512; t += 256) {
      int r = t >> 3, s = t & 7;
      s16x8 v = *(const s16x8*)(Wt + (size_t)(bn + r) * K + k0 + s * 8);
      *(s16x8*)(Bs + r * 64 + ((s ^ (r & 7)) << 3)) = v;
    }
    __syncthreads();
#pragma unroll
    for (int ks = 0; ks < 2; ++ks) {
      s16x8 af[2], bf[2];
#pragma unroll
      for (int mf = 0; mf < 2; ++mf) {
        int r = wm * 32 + mf * 16 + (lane & 15);
        int s = ks * 4 + (lane >> 4);
        af[mf] = *(const s16x8*)(As + r * 64 + ((s ^ (r & 7)) << 3));
      }
#pragma unroll
      for (int nf = 0; nf < 2; ++nf) {
        int r = wn * 32 + nf * 16 + (lane & 15);
        int s = ks * 4 + (lane >> 4);
        bf[nf] = *(const s16x8*)(Bs + r * 64 + ((s ^ (r & 7)) << 3));
      }
#pragma unroll
      for (int mf = 0; mf < 2; ++mf)
#pragma unroll
        for (int nf = 0; nf < 2; ++nf)
          acc[mf][nf] = MFMA(af[mf], bf[nf], acc[mf][nf]);
    }
    __syncthreads();
  }
  // epilogue
#pragma unroll
  for (int mf = 0; mf < 2; ++mf) {
#pragma unroll
    for (int nf = 0; nf < 2; ++nf) {
#pragma unroll
      for (int r = 0; r < 4; ++r) {
        int m = bm + wm * 32 + mf * 16 + (lane >> 4) * 4 + r;
        int n = bn + wn * 32 + nf * 16 + (lane & 15);
        float v = acc[mf][nf][r];
        if (EPI == 0) {
          if (n < 256) {
            qb[(size_t)m * 256 + n] = f2b(v * QSCALE);
          } else if (n < 512) {
            kb[(size_t)m * 256 + (n - 256)] = f2b(v);
          } else {
            int nv = n - 512, h = nv >> 5, d = nv & 31;
            int bb = m >> 9, j = m & 511;
            vt[(size_t)((bb * 8 + h) * 32 + d) * 512 + j] = f2b(v);
          }
        } else if (EPI == 1) {
          outf[(size_t)m * N + n] = v + bias[n] + R[(size_t)m * N + n];
        } else {
          float g = v + bias[n];
          g = 0.5f * g * (1.0f + erff(g * 0.70710678118654752f));
          outb[(size_t)m * N + n] = f2b(g);
        }
      }
    }
  }
}

// ---------------- pair-bias MLP: layer1 VALU -> LDS bf16, layer2 MFMA ------
__global__ __launch_bounds__(256) void pbias_kernel(
    const float* __restrict__ pf, const float* __restrict__ packed,
    const u16* __restrict__ wp2t, const float* __restrict__ bp2,
    u16* __restrict__ biasout) {
  const int bid = blockIdx.x;           // b*512 + i
  const int b = bid >> 9, i = bid & 511;
  const int tid = threadIdx.x;
  const int lane = tid & 63, w = tid >> 6;
  __shared__ float pfl[1536];
  __shared__ u16 h1[512 * 32]; // rows j (64B), 4 slots, swizzle ^(j&3)
  const float4* pfr = (const float4*)(pf + (size_t)(b * 512 + i) * 1536);
#pragma unroll
  for (int t = tid; t < 384; t += 256) ((float4*)pfl)[t] = pfr[t];
  __syncthreads();
  const int j0 = tid, j1 = tid + 256;
  float f0a = pfl[j0 * 3], f1a = pfl[j0 * 3 + 1], f2a = pfl[j0 * 3 + 2];
  float f0b = pfl[j1 * 3], f1b = pfl[j1 * 3 + 1], f2b_ = pfl[j1 * 3 + 2];
  // preload Wp2^T fragments (8 chunks of K=32)
  s16x8 wfrag[8];
#pragma unroll
  for (int c8 = 0; c8 < 8; ++c8)
    wfrag[c8] = *(const s16x8*)(wp2t + (lane & 15) * 256 + c8 * 32 + (lane >> 4) * 8);
  f32x4 fz = {0.f, 0.f, 0.f, 0.f};
  f32x4 racc[8] = {fz, fz, fz, fz, fz, fz, fz, fz};
  const float4* pk4 = (const float4*)packed;
  for (int chunk = 0; chunk < 8; ++chunk) {
    int cc = chunk * 32;
#pragma unroll
    for (int cg = 0; cg < 8; ++cg) {
      float va[4], vb[4];
#pragma unroll
      for (int q = 0; q < 4; ++q) {
        float4 p = pk4[cc + cg * 4 + q];
        float ha = fmaf(f0a, p.x, fmaf(f1a, p.y, fmaf(f2a, p.z, p.w)));
        float hb = fmaf(f0b, p.x, fmaf(f1b, p.y, fmaf(f2b_, p.z, p.w)));
        va[q] = fmaxf(ha, 0.f); vb[q] = fmaxf(hb, 0.f);
      }
      int slot = cg >> 1, sub = (cg & 1) * 4;
      u32x2 wa, wb;
      wa.x = (unsigned)f2b(va[0]) | ((unsigned)f2b(va[1]) << 16);
      wa.y = (unsigned)f2b(va[2]) | ((unsigned)f2b(va[3]) << 16);
      wb.x = (unsigned)f2b(vb[0]) | ((unsigned)f2b(vb[1]) << 16);
      wb.y = (unsigned)f2b(vb[2]) | ((unsigned)f2b(vb[3]) << 16);
      *(u32x2*)(h1 + j0 * 32 + ((slot ^ (j0 & 3)) << 3) + sub) = wa;
      *(u32x2*)(h1 + j1 * 32 + ((slot ^ (j1 & 3)) << 3) + sub) = wb;
    }
    __syncthreads();
#pragma unroll
    for (int jf = 0; jf < 8; ++jf) {
      int r = w * 128 + jf * 16 + (lane & 15);
      s16x8 af = *(const s16x8*)(h1 + r * 32 + (((lane >> 4) ^ (r & 3)) << 3));
      racc[jf] = MFMA(af, wfrag[chunk], racc[jf]);
    }
    __syncthreads();
  }
  // store bias[b][h][i][j] bf16 (h = lane&15 < 8)
  int h = lane & 15;
  if (h < 8) {
    float bb = bp2[h];
    size_t base = ((size_t)(b * 8 + h) * 512 + i) * 512;
#pragma unroll
    for (int jf = 0; jf < 8; ++jf) {
      int jb = w * 128 + jf * 16 + (lane >> 4) * 4;
      u32x2 o;
      o.x = (unsigned)f2b(racc[jf][0] + bb) | ((unsigned)f2b(racc[jf][1] + bb) << 16);
      o.y = (unsigned)f2b(racc[jf][2] + bb) | ((unsigned)f2b(racc[jf][3] + bb) << 16);
      *(u32x2*)(biasout + base + jb) = o;
    }
  }
}

// ---------------- fused flash attention: QK^T + bias + mask + softmax + PV -
__global__ __launch_bounds__(256) void flash_kernel(
    const u16* __restrict__ qb, const u16* __restrict__ kb,
    const u16* __restrict__ vt, const u16* __restrict__ biasin,
    const int* __restrict__ maskd, u16* __restrict__ aout) {
  const int i0 = blockIdx.x * 64, h = blockIdx.y, b = blockIdx.z;
  const int tid = threadIdx.x;
  const int lane = tid & 63, mf = tid >> 6;   // wave owns rows mf*16..+15
  __shared__ u16 qs[64 * 32];    // 4KB  rows i, 4 slots, ^(r&3)
  __shared__ u16 ksh[128 * 32];  // 8KB  rows j
  __shared__ u16 vs[32 * 128];   // 8KB  rows d, 16 slots, low3 ^(d&7)
  __shared__ u16 bs[64 * 128];   // 16KB rows i, 16 slots
  __shared__ u16 ps[4][16 * 64]; // per-wave P, rows i(16), 8 slots, ^(r&7)
  // stage q once
  for (int t = tid; t < 256; t += 256) {
    int r = t >> 2, s = t & 3;
    s16x8 v = *(const s16x8*)(qb + (size_t)(b * 512 + i0 + r) * 256 + h * 32 + s * 8);
    *(s16x8*)(qs + r * 32 + ((s ^ (r & 3)) << 3)) = v;
  }
  f32x4 fz = {0.f, 0.f, 0.f, 0.f};
  f32x4 oacc[2] = {fz, fz};
  float mrun[4] = {-3e38f, -3e38f, -3e38f, -3e38f};
  float lrun[4] = {0.f, 0.f, 0.f, 0.f};
  const int* mrow = maskd + b * 512;
  for (int jc = 0; jc < 4; ++jc) {
    int j0 = jc * 128;
#pragma unroll
    for (int t = tid; t < 512; t += 256) {  // K tile
      int r = t >> 2, s = t & 3;
      s16x8 v = *(const s16x8*)(kb + (size_t)(b * 512 + j0 + r) * 256 + h * 32 + s * 8);
      *(s16x8*)(ksh + r * 32 + ((s ^ (r & 3)) << 3)) = v;
    }
#pragma unroll
    for (int t = tid; t < 512; t += 256) {  // V^T tile
      int r = t >> 4, s = t & 15;
      s16x8 v = *(const s16x8*)(vt + (size_t)((b * 8 + h) * 32 + r) * 512 + j0 + s * 8);
      *(s16x8*)(vs + r * 128 + (((s & 8) | ((s & 7) ^ (r & 7))) << 3)) = v;
    }
#pragma unroll
    for (int t = tid; t < 1024; t += 256) { // bias tile
      int r = t >> 4, s = t & 15;
      s16x8 v = *(const s16x8*)(biasin + ((size_t)((b * 8 + h) * 512 + i0 + r)) * 512 + j0 + s * 8);
      *(s16x8*)(bs + r * 128 + (((s & 8) | ((s & 7) ^ (r & 7))) << 3)) = v;
    }
    __syncthreads();
#pragma unroll
    for (int jt = 0; jt < 2; ++jt) {
      int jj0 = jt * 64;
      int mk[4];
#pragma unroll
      for (int jf = 0; jf < 4; ++jf)
        mk[jf] = mrow[j0 + jj0 + jf * 16 + (lane & 15)];
      int arow = mf * 16 + (lane & 15);
      s16x8 af = *(const s16x8*)(qs + arow * 32 + (((lane >> 4) ^ (arow & 3)) << 3));
      f32x4 sm[4];
#pragma unroll
      for (int jf = 0; jf < 4; ++jf) {
        int brow = jj0 + jf * 16 + (lane & 15);
        s16x8 bfr = *(const s16x8*)(ksh + brow * 32 + (((lane >> 4) ^ (brow & 3)) << 3));
        sm[jf] = MFMA(af, bfr, fz);
      }
      int il = mf * 16 + (lane >> 4) * 4;
#pragma unroll
      for (int jf = 0; jf < 4; ++jf) {
#pragma unroll
        for (int r = 0; r < 4; ++r) {
          int i_loc = il + r;
          int jb = jj0 + jf * 16 + (lane & 15);
          int slot = jb >> 3;
          float bv = b2f(bs[i_loc * 128 + (((slot & 8) | ((slot & 7) ^ (i_loc & 7))) << 3) + (jb & 7)]);
          float sval = sm[jf][r] + bv;
          sm[jf][r] = mk[jf] ? sval : -1e9f;
        }
      }
      float mx[4];
#pragma unroll
      for (int r = 0; r < 4; ++r)
        mx[r] = fmaxf(fmaxf(sm[0][r], sm[1][r]), fmaxf(sm[2][r], sm[3][r]));
#pragma unroll
      for (int d = 1; d < 16; d <<= 1)
#pragma unroll
        for (int r = 0; r < 4; ++r) mx[r] = fmaxf(mx[r], __shfl_xor(mx[r], d));
      float nm[4], sc[4], psum[4];
#pragma unroll
      for (int r = 0; r < 4; ++r) {
        nm[r] = fmaxf(mrun[r], mx[r]);
        sc[r] = __expf(mrun[r] - nm[r]);
        mrun[r] = nm[r];
        psum[r] = 0.f;
      }
#pragma unroll
      for (int jf = 0; jf < 4; ++jf)
#pragma unroll
        for (int r = 0; r < 4; ++r) {
          float p = __expf(sm[jf][r] - nm[r]);
          sm[jf][r] = p; psum[r] += p;
        }
#pragma unroll
      for (int d = 1; d < 16; d <<= 1)
#pragma unroll
        for (int r = 0; r < 4; ++r) psum[r] += __shfl_xor(psum[r], d);
#pragma unroll
      for (int r = 0; r < 4; ++r) lrun[r] = lrun[r] * sc[r] + psum[r];
#pragma unroll
      for (int df = 0; df < 2; ++df)
#pragma unroll
        for (int r = 0; r < 4; ++r) oacc[df][r] *= sc[r];
      // P -> per-wave LDS buffer (D-layout -> A-layout round trip)
      u16* pw = &ps[mf][0];
#pragma unroll
      for (int jf = 0; jf < 4; ++jf) {
        int jcol = jf * 16 + (lane & 15);
        int slot = jcol >> 3, el = jcol & 7;
#pragma unroll
        for (int r = 0; r < 4; ++r) {
          int row = (lane >> 4) * 4 + r;
          pw[row * 64 + ((slot ^ (row & 7)) << 3) + el] = f2b(sm[jf][r]);
        }
      }
#pragma unroll
      for (int kw = 0; kw < 2; ++kw) {
        int prow = lane & 15;
        s16x8 pa = *(const s16x8*)(pw + prow * 64 + (((kw * 4 + (lane >> 4)) ^ (prow & 7)) << 3));
#pragma unroll
        for (int df = 0; df < 2; ++df) {
          int drow = df * 16 + (lane & 15);
          int jcol = jj0 + kw * 32 + ((lane >> 4) << 3);
          int slot = jcol >> 3;
          s16x8 vb = *(const s16x8*)(vs + drow * 128 + (((slot & 8) | ((slot & 7) ^ (drow & 7))) << 3));
          oacc[df] = MFMA(pa, vb, oacc[df]);
        }
      }
    }
    __syncthreads();
  }
#pragma unroll
  for (int r = 0; r < 4; ++r) {
    float inv = 1.0f / lrun[r];
    int i = i0 + mf * 16 + (lane >> 4) * 4 + r;
#pragma unroll
    for (int df = 0; df < 2; ++df) {
      int d = df * 16 + (lane & 15);
      aout[(size_t)(b * 512 + i) * 256 + h * 32 + d] = f2b(oacc[df][r] * inv);
    }
  }
}

// ---------------- LayerNorm over D=256 -------------------------------------
template<bool WB>
__global__ __launch_bounds__(256) void ln_kernel(
    const float* __restrict__ in, const float* __restrict__ g,
    const float* __restrict__ be, float* __restrict__ op,
    u16* __restrict__ ob) {
  int row = blockIdx.x * 4 + (threadIdx.x >> 6);
  int lane = threadIdx.x & 63;
  const float* x = in + (size_t)row * CD;
  float4 v = *(const float4*)&x[lane * 4];
  float s  = v.x + v.y + v.z + v.w;
  float ss = v.x*v.x + v.y*v.y + v.z*v.z + v.w*v.w;
#pragma unroll
  for (int off = 32; off > 0; off >>= 1) {
    s  += __shfl_xor(s, off);
    ss += __shfl_xor(ss, off);
  }
  float mean = s * (1.0f / CD);
  float var  = ss * (1.0f / CD) - mean * mean;
  float inv  = rsqrtf(var + CEPS);
  float4 gg = *(const float4*)&g[lane * 4];
  float4 bb = *(const float4*)&be[lane * 4];
  float4 o;
  o.x = (v.x - mean) * inv * gg.x + bb.x;
  o.y = (v.y - mean) * inv * gg.y + bb.y;
  o.z = (v.z - mean) * inv * gg.z + bb.z;
  o.w = (v.w - mean) * inv * gg.w + bb.w;
  *(float4*)&op[(size_t)row * CD + lane * 4] = o;
  if (WB) {
    u32x2 w; w.x = (unsigned)f2b(o.x) | ((unsigned)f2b(o.y) << 16);
    w.y = (unsigned)f2b(o.z) | ((unsigned)f2b(o.w) << 16);
    *(u32x2*)(ob + (size_t)row * CD + lane * 4) = w;
  }
}

extern "C" void kernel_launch(void* const* d_in, const int* in_sizes, int n_in,
                              void* d_out, int out_size, void* d_ws, size_t ws_size,
                              hipStream_t stream) {
  (void)in_sizes; (void)n_in; (void)out_size; (void)ws_size;
  const float* x    = (const float*)d_in[0];
  const void*  mask = d_in[1];
  const float* pf   = (const float*)d_in[2];
  const float* Wqkv = (const float*)d_in[3];
  const float* Wout = (const float*)d_in[4];
  const float* bout = (const float*)d_in[5];
  const float* Wp1  = (const float*)d_in[6];
  const float* bp1  = (const float*)d_in[7];
  const float* Wp2  = (const float*)d_in[8];
  const float* bp2  = (const float*)d_in[9];
  const float* Wf1  = (const float*)d_in[10];
  const float* bf1  = (const float*)d_in[11];
  const float* Wf2  = (const float*)d_in[12];
  const float* bf2  = (const float*)d_in[13];
  const float* g1   = (const float*)d_in[14];
  const float* b1   = (const float*)d_in[15];
  const float* g2   = (const float*)d_in[16];
  const float* b2   = (const float*)d_in[17];

  char* ws = (char*)d_ws;
  u16* xb     = (u16*)(ws + O_XB);
  u16* qb     = (u16*)(ws + O_QB);
  u16* kb     = (u16*)(ws + O_KB);
  u16* vt     = (u16*)(ws + O_VT);
  u16* wqkvt  = (u16*)(ws + O_WQKVT);
  u16* woutt  = (u16*)(ws + O_WOUTT);
  u16* wf1t   = (u16*)(ws + O_WF1T);
  u16* wf2t   = (u16*)(ws + O_WF2T);
  u16* wp2t   = (u16*)(ws + O_WP2T);
  float* packed = (float*)(ws + O_PACKED);
  int* maskd  = (int*)(ws + O_MASKD);
  u16* biasb  = (u16*)(ws + O_BIAS);
  u16* aout   = (u16*)(ws + O_AOUT);
  float* pre1 = (float*)(ws + O_PRE1);
  float* x1f  = (float*)(ws + O_X1F);
  u16* x1b    = (u16*)(ws + O_X1B);
  u16* h1b    = (u16*)(ws + O_H1B);
  float* pre2 = (float*)(ws + O_PRE2);
  float* out  = (float*)d_out;

  hipLaunchKernelGGL(prep_kernel, dim3(641), dim3(256), 0, stream,
                     x, Wqkv, Wout, Wf1, Wf2, Wp2, Wp1, bp1,
                     xb, wqkvt, woutt, wf1t, wf2t, wp2t, packed);
  hipLaunchKernelGGL(decode_mask_kernel, dim3(1), dim3(256), 0, stream,
                     (const unsigned char*)mask, maskd);
  // qkv = x @ Wqkv  (split epilogue: qb scaled, kb, vt)
  hipLaunchKernelGGL((mgemm<0>), dim3(12, 32), dim3(256), 0, stream,
                     xb, wqkvt, nullptr, nullptr, nullptr, nullptr,
                     qb, kb, vt, M_ROWS, 768, 256);
  // pair bias MLP -> bias[b][h][i][j] bf16
  hipLaunchKernelGGL(pbias_kernel, dim3(2048), dim3(256), 0, stream,
                     pf, packed, wp2t, bp2, biasb);
  // fused attention
  hipLaunchKernelGGL(flash_kernel, dim3(8, 8, 4), dim3(256), 0, stream,
                     qb, kb, vt, biasb, maskd, aout);
  // out proj + bout + residual(x) -> pre1 (f32)
  hipLaunchKernelGGL((mgemm<1>), dim3(4, 32), dim3(256), 0, stream,
                     aout, woutt, bout, x, pre1, nullptr,
                     nullptr, nullptr, nullptr, M_ROWS, 256, 256);
  hipLaunchKernelGGL((ln_kernel<true>), dim3(M_ROWS / 4), dim3(256), 0, stream,
                     pre1, g1, b1, x1f, x1b);
  // FFN1: GELU -> h1b bf16
  hipLaunchKernelGGL((mgemm<2>), dim3(16, 32), dim3(256), 0, stream,
                     x1b, wf1t, bf1, nullptr, nullptr, h1b,
                     nullptr, nullptr, nullptr, M_ROWS, 1024, 256);
  // FFN2 + bf2 + residual(x1f) -> pre2 (f32)
  hipLaunchKernelGGL((mgemm<1>), dim3(4, 32), dim3(256), 0, stream,
                     h1b, wf2t, bf2, x1f, pre2, nullptr,
                     nullptr, nullptr, nullptr, M_ROWS, 256, 1024);
  hipLaunchKernelGGL((ln_kernel<false>), dim3(M_ROWS / 4), dim3(256), 0, stream,
                     pre2, g2, b2, out, nullptr);
}

// Round 5
// 140.602 us; speedup vs baseline: 3.4887x; 2.6116x over previous
//
#include <hip/hip_runtime.h>
#include <math.h>

typedef unsigned short u16;
typedef short s16x8 __attribute__((ext_vector_type(8)));
typedef float f32x4 __attribute__((ext_vector_type(4)));
typedef unsigned int u32x2 __attribute__((ext_vector_type(2)));

constexpr int CB = 4, CN = 512, CD = 256, CH = 8, CHD = 32;
constexpr float CEPS = 1e-5f;
constexpr int M_ROWS = CB * CN; // 2048
constexpr float QSCALE = 0.17677669529663687f; // 32^-0.5

// ---- workspace layout (byte offsets) ----
constexpr size_t O_XB    = 0;                      // u16 [2048][256]
constexpr size_t O_QB    = 1048576;                // u16 [2048][256] (pre-scaled)
constexpr size_t O_KB    = 2097152;                // u16 [2048][256]
constexpr size_t O_VT    = 3145728;                // u16 [4][8][32][512]
constexpr size_t O_WQKVT = 4194304;                // u16 [768][256]
constexpr size_t O_WOUTT = O_WQKVT + 393216;       // u16 [256][256]
constexpr size_t O_WF1T  = O_WOUTT + 131072;       // u16 [1024][256]
constexpr size_t O_WF2T  = O_WF1T + 524288;        // u16 [256][1024]
constexpr size_t O_WP2T  = O_WF2T + 524288;        // u16 [16][256] (pad h>=8 = 0)
constexpr size_t O_PACKED= O_WP2T + 8192;          // f32 [256][4] (w0,w1,w2,b)
constexpr size_t O_MASKD = O_PACKED + 4096;        // int [2048]
constexpr size_t O_BIAS  = O_MASKD + 8192;         // u16 [4][8][512][512]
constexpr size_t O_AOUT  = O_BIAS + 16777216;      // u16 [2048][256]
constexpr size_t O_PRE1  = O_AOUT + 1048576;       // f32 [2048][256]
constexpr size_t O_X1F   = O_PRE1 + 2097152;       // f32 [2048][256]
constexpr size_t O_X1B   = O_X1F + 2097152;        // u16 [2048][256]
constexpr size_t O_H1B   = O_X1B + 1048576;        // u16 [2048][1024]
constexpr size_t O_PRE2  = O_H1B + 4194304;        // f32 [2048][256]

__device__ inline u16 f2b(float f) {
  union { float f; unsigned u; } v{f};
  return (u16)((v.u + 0x7FFFu + ((v.u >> 16) & 1u)) >> 16);
}
__device__ inline float b2f(u16 b) {
  union { unsigned u; float f; } v{(unsigned)b << 16};
  return v.f;
}
__device__ inline f32x4 MFMA(s16x8 a, s16x8 b, f32x4 c) {
  return __builtin_amdgcn_mfma_f32_16x16x32_bf16(a, b, c, 0, 0, 0);
}
__device__ inline unsigned cvtpk(float lo, float hi) {
  unsigned r;
  asm("v_cvt_pk_bf16_f32 %0, %1, %2" : "=v"(r) : "v"(lo), "v"(hi));
  return r;
}

// ---------------- mask decode (robust to bool / int32 / float32) -----------
__global__ void decode_mask_kernel(const unsigned char* __restrict__ raw,
                                   int* __restrict__ mout) {
  __shared__ int mode_max;
  if (threadIdx.x == 0) mode_max = 0;
  __syncthreads();
  int lm = 0;
  for (int i = threadIdx.x; i < CB*CN; i += 256)
    if ((i & 3) != 0) lm = max(lm, (int)raw[i]);
  atomicMax(&mode_max, lm);
  __syncthreads();
  int mv = mode_max;
  for (int i = threadIdx.x; i < CB*CN; i += 256) {
    int val;
    if (mv == 0)      val = (((const int*)raw)[i] != 0);
    else if (mv == 1) val = (raw[i] != 0);
    else              val = (((const unsigned int*)raw)[i] != 0);
    mout[i] = val;
  }
}

// ---------------- prep: bf16 convert + weight transposes -------------------
__global__ __launch_bounds__(256) void prep_kernel(
    const float* __restrict__ x, const float* __restrict__ Wqkv,
    const float* __restrict__ Wout, const float* __restrict__ Wf1,
    const float* __restrict__ Wf2, const float* __restrict__ Wp2,
    const float* __restrict__ Wp1, const float* __restrict__ bp1,
    u16* __restrict__ xb, u16* __restrict__ wqkvt, u16* __restrict__ woutt,
    u16* __restrict__ wf1t, u16* __restrict__ wf2t, u16* __restrict__ wp2t,
    float* __restrict__ packed) {
  int blk = blockIdx.x, tid = threadIdx.x;
  if (blk < 256) {            // x -> xb
    for (int t = tid; t < 512; t += 256) {
      float4 v = ((const float4*)x)[blk * 512 + t];
      u16 o0 = f2b(v.x), o1 = f2b(v.y), o2 = f2b(v.z), o3 = f2b(v.w);
      u32x2 w; w.x = (unsigned)o0 | ((unsigned)o1 << 16);
      w.y = (unsigned)o2 | ((unsigned)o3 << 16);
      *(u32x2*)(xb + (size_t)(blk * 512 + t) * 4) = w;
    }
  } else if (blk < 352) {     // Wqkv^T
    int o0 = (blk - 256) * 2048;
    for (int t = tid; t < 2048; t += 256) {
      int o = o0 + t, n = o >> 8, k = o & 255;
      wqkvt[o] = f2b(Wqkv[k * 768 + n]);
    }
  } else if (blk < 384) {     // Wout^T
    int o0 = (blk - 352) * 2048;
    for (int t = tid; t < 2048; t += 256) {
      int o = o0 + t, n = o >> 8, k = o & 255;
      woutt[o] = f2b(Wout[k * 256 + n]);
    }
  } else if (blk < 512) {     // Wf1^T
    int o0 = (blk - 384) * 2048;
    for (int t = tid; t < 2048; t += 256) {
      int o = o0 + t, n = o >> 8, k = o & 255;
      wf1t[o] = f2b(Wf1[k * 1024 + n]);
    }
  } else if (blk < 640) {     // Wf2^T
    int o0 = (blk - 512) * 2048;
    for (int t = tid; t < 2048; t += 256) {
      int o = o0 + t, n = o >> 10, k = o & 1023;
      wf2t[o] = f2b(Wf2[k * 256 + n]);
    }
  } else {                    // Wp2^T (padded) + packed Wp1/bp1
    for (int t = tid; t < 4096; t += 256) {
      int h = t >> 8, c = t & 255;
      wp2t[t] = (h < 8) ? f2b(Wp2[c * 8 + h]) : (u16)0;
    }
    if (tid < 256) {
      float4 p; p.x = Wp1[tid]; p.y = Wp1[256 + tid]; p.z = Wp1[512 + tid];
      p.w = bp1[tid];
      ((float4*)packed)[tid] = p;
    }
  }
}

// ---------------- bf16 MFMA GEMM, 64x64 tile, BK=64 ------------------------
// EPI 0: qkv split (q scaled, k, v transposed)  1: +bias+R -> f32   2: +bias,GELU -> bf16
template<int EPI>
__global__ __launch_bounds__(256) void mgemm(
    const u16* __restrict__ A, const u16* __restrict__ Wt,
    const float* __restrict__ bias, const float* __restrict__ R,
    float* __restrict__ outf, u16* __restrict__ outb,
    u16* __restrict__ qb, u16* __restrict__ kb, u16* __restrict__ vt,
    int M, int N, int K) {
  __shared__ u16 As[64 * 64];
  __shared__ u16 Bs[64 * 64];
  const int tid = threadIdx.x;
  const int lane = tid & 63, w = tid >> 6;
  const int wm = w >> 1, wn = w & 1;
  const int bm = blockIdx.y * 64, bn = blockIdx.x * 64;
  f32x4 fz = {0.f, 0.f, 0.f, 0.f};
  f32x4 acc[2][2] = {{fz, fz}, {fz, fz}};
  for (int k0 = 0; k0 < K; k0 += 64) {
#pragma unroll
    for (int t = tid; t < 512; t += 256) {
      int r = t >> 3, s = t & 7;
      s16x8 v = *(const s16x8*)(A + (size_t)(bm + r) * K + k0 + s * 8);
      *(s16x8*)(As + r * 64 + ((s ^ (r & 7)) << 3)) = v;
    }
#pragma unroll
    for (int t = tid; t < 512; t += 256) {
      int r = t >> 3, s = t & 7;
      s16x8 v = *(const s16x8*)(Wt + (size_t)(bn + r) * K + k0 + s * 8);
      *(s16x8*)(Bs + r * 64 + ((s ^ (r & 7)) << 3)) = v;
    }
    __syncthreads();
#pragma unroll
    for (int ks = 0; ks < 2; ++ks) {
      s16x8 af[2], bf[2];
#pragma unroll
      for (int mf = 0; mf < 2; ++mf) {
        int r = wm * 32 + mf * 16 + (lane & 15);
        int s = ks * 4 + (lane >> 4);
        af[mf] = *(const s16x8*)(As + r * 64 + ((s ^ (r & 7)) << 3));
      }
#pragma unroll
      for (int nf = 0; nf < 2; ++nf) {
        int r = wn * 32 + nf * 16 + (lane & 15);
        int s = ks * 4 + (lane >> 4);
        bf[nf] = *(const s16x8*)(Bs + r * 64 + ((s ^ (r & 7)) << 3));
      }
#pragma unroll
      for (int mf = 0; mf < 2; ++mf)
#pragma unroll
        for (int nf = 0; nf < 2; ++nf)
          acc[mf][nf] = MFMA(af[mf], bf[nf], acc[mf][nf]);
    }
    __syncthreads();
  }
  // epilogue
#pragma unroll
  for (int mf = 0; mf < 2; ++mf) {
#pragma unroll
    for (int nf = 0; nf < 2; ++nf) {
#pragma unroll
      for (int r = 0; r < 4; ++r) {
        int m = bm + wm * 32 + mf * 16 + (lane >> 4) * 4 + r;
        int n = bn + wn * 32 + nf * 16 + (lane & 15);
        float v = acc[mf][nf][r];
        if (EPI == 0) {
          if (n < 256) {
            qb[(size_t)m * 256 + n] = f2b(v * QSCALE);
          } else if (n < 512) {
            kb[(size_t)m * 256 + (n - 256)] = f2b(v);
          } else {
            int nv = n - 512, h = nv >> 5, d = nv & 31;
            int bb = m >> 9, j = m & 511;
            vt[(size_t)((bb * 8 + h) * 32 + d) * 512 + j] = f2b(v);
          }
        } else if (EPI == 1) {
          outf[(size_t)m * N + n] = v + bias[n] + R[(size_t)m * N + n];
        } else {
          float g = v + bias[n];
          g = 0.5f * g * (1.0f + erff(g * 0.70710678118654752f));
          outb[(size_t)m * N + n] = f2b(g);
        }
      }
    }
  }
}

// ---------------- pair-bias MLP v2: layer1 in registers -> direct MFMA -----
// Block = one (b,i) row pair-feature strip; 4 waves x 128 j each.
// Lane computes its OWN MFMA A-fragment: rows j = tile + (lane&15),
// channels chunk*32 + (lane>>4)*8 + e  -- no h1 LDS buffer, no per-chunk
// barriers, hardware v_cvt_pk_bf16_f32 for conversion.
__global__ __launch_bounds__(256) void pbias_kernel(
    const float* __restrict__ pf, const float* __restrict__ packed,
    const u16* __restrict__ wp2t, const float* __restrict__ bp2,
    u16* __restrict__ biasout) {
  const int bid = blockIdx.x;           // b*512 + i
  const int b = bid >> 9, i = bid & 511;
  const int tid = threadIdx.x;
  const int lane = tid & 63, w = tid >> 6;
  const int q = lane >> 4, hr = lane & 15;
  __shared__ float pk[256 * 4];         // packed channel params (4KB)
  for (int t = tid; t < 256; t += 256)
    ((float4*)pk)[t] = ((const float4*)packed)[t];
  // row features for 8 tiles of 16 rows: j = w*128 + t*16 + hr
  const float* pfb = pf + (size_t)(b * 512 + i) * 1536;
  float f0[8], f1[8], f2[8];
#pragma unroll
  for (int t = 0; t < 8; ++t) {
    int j = w * 128 + t * 16 + hr;
    f0[t] = pfb[j * 3 + 0];
    f1[t] = pfb[j * 3 + 1];
    f2[t] = pfb[j * 3 + 2];
  }
  __syncthreads();
  f32x4 fz = {0.f, 0.f, 0.f, 0.f};
  f32x4 acc[8] = {fz, fz, fz, fz, fz, fz, fz, fz};
  for (int chunk = 0; chunk < 8; ++chunk) {
    // B-fragment for this K-chunk (16B global load, L1-hot)
    s16x8 wfrag = *(const s16x8*)(wp2t + hr * 256 + chunk * 32 + q * 8);
    // 8 channel param vectors (broadcast LDS reads within 16-lane groups)
    float4 cp[8];
#pragma unroll
    for (int e = 0; e < 8; ++e)
      cp[e] = ((const float4*)pk)[chunk * 32 + q * 8 + e];
#pragma unroll
    for (int t = 0; t < 8; ++t) {
      float hv[8];
#pragma unroll
      for (int e = 0; e < 8; ++e) {
        float h = fmaf(f0[t], cp[e].x, fmaf(f1[t], cp[e].y, fmaf(f2[t], cp[e].z, cp[e].w)));
        hv[e] = fmaxf(h, 0.f);
      }
      union { unsigned u[4]; s16x8 v; } af;
      af.u[0] = cvtpk(hv[0], hv[1]);
      af.u[1] = cvtpk(hv[2], hv[3]);
      af.u[2] = cvtpk(hv[4], hv[5]);
      af.u[3] = cvtpk(hv[6], hv[7]);
      acc[t] = MFMA(af.v, wfrag, acc[t]);
    }
  }
  // epilogue: C frag col = hr (head), rows = q*4 + r (4 consecutive j)
  if (hr < 8) {
    float bb = bp2[hr];
    size_t base = ((size_t)(b * 8 + hr) * 512 + i) * 512;
#pragma unroll
    for (int t = 0; t < 8; ++t) {
      int j0 = w * 128 + t * 16 + q * 4;
      u32x2 o;
      o.x = cvtpk(acc[t][0] + bb, acc[t][1] + bb);
      o.y = cvtpk(acc[t][2] + bb, acc[t][3] + bb);
      *(u32x2*)(biasout + base + j0) = o;
    }
  }
}

// ---------------- fused flash attention: QK^T + bias + mask + softmax + PV -
__global__ __launch_bounds__(256) void flash_kernel(
    const u16* __restrict__ qb, const u16* __restrict__ kb,
    const u16* __restrict__ vt, const u16* __restrict__ biasin,
    const int* __restrict__ maskd, u16* __restrict__ aout) {
  const int i0 = blockIdx.x * 64, h = blockIdx.y, b = blockIdx.z;
  const int tid = threadIdx.x;
  const int lane = tid & 63, mf = tid >> 6;   // wave owns rows mf*16..+15
  __shared__ u16 qs[64 * 32];    // 4KB  rows i, 4 slots, ^(r&3)
  __shared__ u16 ksh[128 * 32];  // 8KB  rows j
  __shared__ u16 vs[32 * 128];   // 8KB  rows d, 16 slots, low3 ^(d&7)
  __shared__ u16 bs[64 * 128];   // 16KB rows i, 16 slots
  __shared__ u16 ps[4][16 * 64]; // per-wave P, rows i(16), 8 slots, ^(r&7)
  // stage q once
  for (int t = tid; t < 256; t += 256) {
    int r = t >> 2, s = t & 3;
    s16x8 v = *(const s16x8*)(qb + (size_t)(b * 512 + i0 + r) * 256 + h * 32 + s * 8);
    *(s16x8*)(qs + r * 32 + ((s ^ (r & 3)) << 3)) = v;
  }
  f32x4 fz = {0.f, 0.f, 0.f, 0.f};
  f32x4 oacc[2] = {fz, fz};
  float mrun[4] = {-3e38f, -3e38f, -3e38f, -3e38f};
  float lrun[4] = {0.f, 0.f, 0.f, 0.f};
  const int* mrow = maskd + b * 512;
  for (int jc = 0; jc < 4; ++jc) {
    int j0 = jc * 128;
#pragma unroll
    for (int t = tid; t < 512; t += 256) {  // K tile
      int r = t >> 2, s = t & 3;
      s16x8 v = *(const s16x8*)(kb + (size_t)(b * 512 + j0 + r) * 256 + h * 32 + s * 8);
      *(s16x8*)(ksh + r * 32 + ((s ^ (r & 3)) << 3)) = v;
    }
#pragma unroll
    for (int t = tid; t < 512; t += 256) {  // V^T tile
      int r = t >> 4, s = t & 15;
      s16x8 v = *(const s16x8*)(vt + (size_t)((b * 8 + h) * 32 + r) * 512 + j0 + s * 8);
      *(s16x8*)(vs + r * 128 + (((s & 8) | ((s & 7) ^ (r & 7))) << 3)) = v;
    }
#pragma unroll
    for (int t = tid; t < 1024; t += 256) { // bias tile
      int r = t >> 4, s = t & 15;
      s16x8 v = *(const s16x8*)(biasin + ((size_t)((b * 8 + h) * 512 + i0 + r)) * 512 + j0 + s * 8);
      *(s16x8*)(bs + r * 128 + (((s & 8) | ((s & 7) ^ (r & 7))) << 3)) = v;
    }
    __syncthreads();
#pragma unroll
    for (int jt = 0; jt < 2; ++jt) {
      int jj0 = jt * 64;
      int mk[4];
#pragma unroll
      for (int jf = 0; jf < 4; ++jf)
        mk[jf] = mrow[j0 + jj0 + jf * 16 + (lane & 15)];
      int arow = mf * 16 + (lane & 15);
      s16x8 af = *(const s16x8*)(qs + arow * 32 + (((lane >> 4) ^ (arow & 3)) << 3));
      f32x4 sm[4];
#pragma unroll
      for (int jf = 0; jf < 4; ++jf) {
        int brow = jj0 + jf * 16 + (lane & 15);
        s16x8 bfr = *(const s16x8*)(ksh + brow * 32 + (((lane >> 4) ^ (brow & 3)) << 3));
        sm[jf] = MFMA(af, bfr, fz);
      }
      int il = mf * 16 + (lane >> 4) * 4;
#pragma unroll
      for (int jf = 0; jf < 4; ++jf) {
#pragma unroll
        for (int r = 0; r < 4; ++r) {
          int i_loc = il + r;
          int jb = jj0 + jf * 16 + (lane & 15);
          int slot = jb >> 3;
          float bv = b2f(bs[i_loc * 128 + (((slot & 8) | ((slot & 7) ^ (i_loc & 7))) << 3) + (jb & 7)]);
          float sval = sm[jf][r] + bv;
          sm[jf][r] = mk[jf] ? sval : -1e9f;
        }
      }
      float mx[4];
#pragma unroll
      for (int r = 0; r < 4; ++r)
        mx[r] = fmaxf(fmaxf(sm[0][r], sm[1][r]), fmaxf(sm[2][r], sm[3][r]));
#pragma unroll
      for (int d = 1; d < 16; d <<= 1)
#pragma unroll
        for (int r = 0; r < 4; ++r) mx[r] = fmaxf(mx[r], __shfl_xor(mx[r], d));
      float nm[4], sc[4], psum[4];
#pragma unroll
      for (int r = 0; r < 4; ++r) {
        nm[r] = fmaxf(mrun[r], mx[r]);
        sc[r] = __expf(mrun[r] - nm[r]);
        mrun[r] = nm[r];
        psum[r] = 0.f;
      }
#pragma unroll
      for (int jf = 0; jf < 4; ++jf)
#pragma unroll
        for (int r = 0; r < 4; ++r) {
          float p = __expf(sm[jf][r] - nm[r]);
          sm[jf][r] = p; psum[r] += p;
        }
#pragma unroll
      for (int d = 1; d < 16; d <<= 1)
#pragma unroll
        for (int r = 0; r < 4; ++r) psum[r] += __shfl_xor(psum[r], d);
#pragma unroll
      for (int r = 0; r < 4; ++r) lrun[r] = lrun[r] * sc[r] + psum[r];
#pragma unroll
      for (int df = 0; df < 2; ++df)
#pragma unroll
        for (int r = 0; r < 4; ++r) oacc[df][r] *= sc[r];
      // P -> per-wave LDS buffer (D-layout -> A-layout round trip)
      u16* pw = &ps[mf][0];
#pragma unroll
      for (int jf = 0; jf < 4; ++jf) {
        int jcol = jf * 16 + (lane & 15);
        int slot = jcol >> 3, el = jcol & 7;
#pragma unroll
        for (int r = 0; r < 4; ++r) {
          int row = (lane >> 4) * 4 + r;
          pw[row * 64 + ((slot ^ (row & 7)) << 3) + el] = f2b(sm[jf][r]);
        }
      }
#pragma unroll
      for (int kw = 0; kw < 2; ++kw) {
        int prow = lane & 15;
        s16x8 pa = *(const s16x8*)(pw + prow * 64 + (((kw * 4 + (lane >> 4)) ^ (prow & 7)) << 3));
#pragma unroll
        for (int df = 0; df < 2; ++df) {
          int drow = df * 16 + (lane & 15);
          int jcol = jj0 + kw * 32 + ((lane >> 4) << 3);
          int slot = jcol >> 3;
          s16x8 vb = *(const s16x8*)(vs + drow * 128 + (((slot & 8) | ((slot & 7) ^ (drow & 7))) << 3));
          oacc[df] = MFMA(pa, vb, oacc[df]);
        }
      }
    }
    __syncthreads();
  }
#pragma unroll
  for (int r = 0; r < 4; ++r) {
    float inv = 1.0f / lrun[r];
    int i = i0 + mf * 16 + (lane >> 4) * 4 + r;
#pragma unroll
    for (int df = 0; df < 2; ++df) {
      int d = df * 16 + (lane & 15);
      aout[(size_t)(b * 512 + i) * 256 + h * 32 + d] = f2b(oacc[df][r] * inv);
    }
  }
}

// ---------------- LayerNorm over D=256 -------------------------------------
template<bool WB>
__global__ __launch_bounds__(256) void ln_kernel(
    const float* __restrict__ in, const float* __restrict__ g,
    const float* __restrict__ be, float* __restrict__ op,
    u16* __restrict__ ob) {
  int row = blockIdx.x * 4 + (threadIdx.x >> 6);
  int lane = threadIdx.x & 63;
  const float* x = in + (size_t)row * CD;
  float4 v = *(const float4*)&x[lane * 4];
  float s  = v.x + v.y + v.z + v.w;
  float ss = v.x*v.x + v.y*v.y + v.z*v.z + v.w*v.w;
#pragma unroll
  for (int off = 32; off > 0; off >>= 1) {
    s  += __shfl_xor(s, off);
    ss += __shfl_xor(ss, off);
  }
  float mean = s * (1.0f / CD);
  float var  = ss * (1.0f / CD) - mean * mean;
  float inv  = rsqrtf(var + CEPS);
  float4 gg = *(const float4*)&g[lane * 4];
  float4 bb = *(const float4*)&be[lane * 4];
  float4 o;
  o.x = (v.x - mean) * inv * gg.x + bb.x;
  o.y = (v.y - mean) * inv * gg.y + bb.y;
  o.z = (v.z - mean) * inv * gg.z + bb.z;
  o.w = (v.w - mean) * inv * gg.w + bb.w;
  *(float4*)&op[(size_t)row * CD + lane * 4] = o;
  if (WB) {
    u32x2 w; w.x = (unsigned)f2b(o.x) | ((unsigned)f2b(o.y) << 16);
    w.y = (unsigned)f2b(o.z) | ((unsigned)f2b(o.w) << 16);
    *(u32x2*)(ob + (size_t)row * CD + lane * 4) = w;
  }
}

extern "C" void kernel_launch(void* const* d_in, const int* in_sizes, int n_in,
                              void* d_out, int out_size, void* d_ws, size_t ws_size,
                              hipStream_t stream) {
  (void)in_sizes; (void)n_in; (void)out_size; (void)ws_size;
  const float* x    = (const float*)d_in[0];
  const void*  mask = d_in[1];
  const float* pf   = (const float*)d_in[2];
  const float* Wqkv = (const float*)d_in[3];
  const float* Wout = (const float*)d_in[4];
  const float* bout = (const float*)d_in[5];
  const float* Wp1  = (const float*)d_in[6];
  const float* bp1  = (const float*)d_in[7];
  const float* Wp2  = (const float*)d_in[8];
  const float* bp2  = (const float*)d_in[9];
  const float* Wf1  = (const float*)d_in[10];
  const float* bf1  = (const float*)d_in[11];
  const float* Wf2  = (const float*)d_in[12];
  const float* bf2  = (const float*)d_in[13];
  const float* g1   = (const float*)d_in[14];
  const float* b1   = (const float*)d_in[15];
  const float* g2   = (const float*)d_in[16];
  const float* b2   = (const float*)d_in[17];

  char* ws = (char*)d_ws;
  u16* xb     = (u16*)(ws + O_XB);
  u16* qb     = (u16*)(ws + O_QB);
  u16* kb     = (u16*)(ws + O_KB);
  u16* vt     = (u16*)(ws + O_VT);
  u16* wqkvt  = (u16*)(ws + O_WQKVT);
  u16* woutt  = (u16*)(ws + O_WOUTT);
  u16* wf1t   = (u16*)(ws + O_WF1T);
  u16* wf2t   = (u16*)(ws + O_WF2T);
  u16* wp2t   = (u16*)(ws + O_WP2T);
  float* packed = (float*)(ws + O_PACKED);
  int* maskd  = (int*)(ws + O_MASKD);
  u16* biasb  = (u16*)(ws + O_BIAS);
  u16* aout   = (u16*)(ws + O_AOUT);
  float* pre1 = (float*)(ws + O_PRE1);
  float* x1f  = (float*)(ws + O_X1F);
  u16* x1b    = (u16*)(ws + O_X1B);
  u16* h1b    = (u16*)(ws + O_H1B);
  float* pre2 = (float*)(ws + O_PRE2);
  float* out  = (float*)d_out;

  hipLaunchKernelGGL(prep_kernel, dim3(641), dim3(256), 0, stream,
                     x, Wqkv, Wout, Wf1, Wf2, Wp2, Wp1, bp1,
                     xb, wqkvt, woutt, wf1t, wf2t, wp2t, packed);
  hipLaunchKernelGGL(decode_mask_kernel, dim3(1), dim3(256), 0, stream,
                     (const unsigned char*)mask, maskd);
  // qkv = x @ Wqkv  (split epilogue: qb scaled, kb, vt)
  hipLaunchKernelGGL((mgemm<0>), dim3(12, 32), dim3(256), 0, stream,
                     xb, wqkvt, nullptr, nullptr, nullptr, nullptr,
                     qb, kb, vt, M_ROWS, 768, 256);
  // pair bias MLP -> bias[b][h][i][j] bf16
  hipLaunchKernelGGL(pbias_kernel, dim3(2048), dim3(256), 0, stream,
                     pf, packed, wp2t, bp2, biasb);
  // fused attention
  hipLaunchKernelGGL(flash_kernel, dim3(8, 8, 4), dim3(256), 0, stream,
                     qb, kb, vt, biasb, maskd, aout);
  // out proj + bout + residual(x) -> pre1 (f32)
  hipLaunchKernelGGL((mgemm<1>), dim3(4, 32), dim3(256), 0, stream,
                     aout, woutt, bout, x, pre1, nullptr,
                     nullptr, nullptr, nullptr, M_ROWS, 256, 256);
  hipLaunchKernelGGL((ln_kernel<true>), dim3(M_ROWS / 4), dim3(256), 0, stream,
                     pre1, g1, b1, x1f, x1b);
  // FFN1: GELU -> h1b bf16
  hipLaunchKernelGGL((mgemm<2>), dim3(16, 32), dim3(256), 0, stream,
                     x1b, wf1t, bf1, nullptr, nullptr, h1b,
                     nullptr, nullptr, nullptr, M_ROWS, 1024, 256);
  // FFN2 + bf2 + residual(x1f) -> pre2 (f32)
  hipLaunchKernelGGL((mgemm<1>), dim3(4, 32), dim3(256), 0, stream,
                     h1b, wf2t, bf2, x1f, pre2, nullptr,
                     nullptr, nullptr, nullptr, M_ROWS, 256, 1024);
  hipLaunchKernelGGL((ln_kernel<false>), dim3(M_ROWS / 4), dim3(256), 0, stream,
                     pre2, g2, b2, out, nullptr);
}